// Round 3
// baseline (256.542 us; speedup 1.0000x reference)
//
#include <hip/hip_runtime.h>

typedef unsigned short u16;
typedef __bf16 bf16x8 __attribute__((ext_vector_type(8)));
typedef float f32x4 __attribute__((ext_vector_type(4)));

#define HH  56
#define WW  56
#define HW  3136      // 56*56
#define CC  256
#define NB  8
#define CKP 2048      // c*7 padded to c*8: channel j's taps = cols j*8..j*8+7
#define KS1 2         // split-K factor GEMM1 (49 iters -> 24/25)

// round-to-nearest-even fp32 -> bf16 (bit pattern) — for non-hot paths
__device__ __forceinline__ u16 f2bf(float f) {
  unsigned int u = __float_as_uint(f);
  u += 0x7fffu + ((u >> 16) & 1u);
  return (u16)(u >> 16);
}
__device__ __forceinline__ float bf2f(u16 v) {
  return __uint_as_float((unsigned)v << 16);
}

// async global->LDS DMA, 16B per lane; dest = wave-uniform base + lane*16
__device__ __forceinline__ void lds_load16(const void* g, void* l) {
  __builtin_amdgcn_global_load_lds(
      (const __attribute__((address_space(1))) void*)g,
      (__attribute__((address_space(3))) void*)l, 16, 0, 0);
}

// compile-time memory reorder fence (0 instructions)
#define MEMFENCE() asm volatile("" ::: "memory")

// ---------------------------------------------------------------------------
// pass1: t1b = bf16(p1w * x), xb = bf16(x).  Fully coalesced float4 reads.
// grid = N*C*HW/4/256 = 6272
// ---------------------------------------------------------------------------
__global__ void pass1(const float* __restrict__ x, const float* __restrict__ p1w,
                      u16* __restrict__ t1b, u16* __restrict__ xb) {
  int i = blockIdx.x * 256 + threadIdx.x;        // over N*C*HW/4
  int cw = i % (CC * HW / 4);                    // p1w broadcast over n
  float4 xv = ((const float4*)x)[i];
  float4 wv = ((const float4*)p1w)[cw];
  uint2 xo = make_uint2((unsigned)f2bf(xv.x) | ((unsigned)f2bf(xv.y) << 16),
                        (unsigned)f2bf(xv.z) | ((unsigned)f2bf(xv.w) << 16));
  ((uint2*)xb)[i] = xo;
  uint2 to = make_uint2((unsigned)f2bf(xv.x * wv.x) | ((unsigned)f2bf(xv.y * wv.y) << 16),
                        (unsigned)f2bf(xv.z * wv.z) | ((unsigned)f2bf(xv.w * wv.w) << 16));
  ((uint2*)t1b)[i] = to;
}

// ---------------------------------------------------------------------------
// gemm1f (R11): fused NT GEMM (split-K=2), 128x128 tile, BK=64.
// Counted-vmcnt pipeline: raw s_barrier + manual s_waitcnt vmcnt(4) so the
// 4 PF vector loads (next-next iteration's B sources) stay in flight ACROSS
// the barrier with a full region of latency cover.  The manual wait drains
// only this region's 4 global_load_lds (A DMA for it+1).
//   B rows j*8+k (k<7) = masked taps of t2[j]; row j*8+7 = t1[j] (G-row).
// Writes fp32 partials Cp[ks][nb][256][CKP].  grid = (2, 16, NB*KS1)
// ---------------------------------------------------------------------------
__global__ __launch_bounds__(256)
void gemm1f(const u16* __restrict__ A, const u16* __restrict__ t1b,
            float* __restrict__ Cp) {
  __shared__ u16 As0[128 * 64], As1[128 * 64];
  __shared__ u16 Bs0[128 * 64], Bs1[128 * 64];

  const int z = blockIdx.z, nb = z / KS1, ks = z % KS1;
  const int it0 = 49 * ks / KS1, it1 = 49 * (ks + 1) / KS1;  // it0 even (0, 24)
  const int itL = it1 - 1;
  const u16* Ab  = A   + (long)nb * CC * HW;
  const u16* t1n = t1b + (long)nb * CC * HW;
  const int m0 = blockIdx.x * 128, n0 = blockIdx.y * 128;
  const int jb = blockIdx.y * 16;                 // first channel of tile
  const int t = threadIdx.x;
  const int lane = t & 63, wave = t >> 6;
  const int wm = wave & 1, wn = wave >> 1;        // 2x2 waves, 64x64 each
  const int lm = lane & 15, quad = lane >> 4;

  // B-gen mapping
  const int jl = (t >> 3) & 15, pc = t & 7, hf = t >> 7;   // hf wave-uniform
  const int j  = jb + jl;
  const int jm = (j + CC - 1) & (CC - 1);
  const u16* arow = t1n + (long)j  * HW;
  const u16* wrow = t1n + (long)jm * HW;

  f32x4 acc[4][4];
#pragma unroll
  for (int a = 0; a < 4; ++a)
#pragma unroll
    for (int b = 0; b < 4; ++b) acc[a][b] = (f32x4)0.0f;

  // A staging geometry: 1024 chunks of 16B, 4 per thread, XOR swizzle
  int rowc[4], colc[4];
#pragma unroll
  for (int ci = 0; ci < 4; ++ci) {
    int c = t + ci * 256;
    rowc[ci] = c >> 3;
    colc[ci] = ((c & 7) ^ (rowc[ci] & 7)) * 8;
  }

  // two named prefetch register sets (even/odd iterations) — static indexing
  __attribute__((aligned(16))) u16 ArE[8], ArO[8];
  __attribute__((aligned(16))) u16 WdE[24], WdO[24];

#define DMA1(AsD, itn) do { const int k0_ = (itn) * 64;                        \
    _Pragma("unroll")                                                          \
    for (int ci = 0; ci < 4; ++ci)                                             \
      lds_load16(Ab + (long)(m0 + rowc[ci]) * HW + k0_ + colc[ci],             \
                 &AsD[(t + ci * 256) * 8]); } while (0)

#define PF1(Ar, Wd, itn) do { const int p8_ = (itn) * 64 + pc * 8;             \
    *(uint4*)(Ar) = *(const uint4*)&arow[p8_];                                 \
    _Pragma("unroll")                                                          \
    for (int L = 0; L < 3; ++L) {                                              \
      int ad = p8_ - 8 + L * 8;                                                \
      ad = ad < 0 ? 0 : (ad > HW - 8 ? HW - 8 : ad);                           \
      *(uint4*)&(Wd)[L * 8] = *(const uint4*)&wrow[ad]; } } while (0)

#define BUILD1(Ar, Wd, BsD, itn) do {                                          \
    const int p8_ = (itn) * 64 + pc * 8;                                       \
    const int w0t_ = p8_ % 56;                                                 \
    int wvx_[8];                                                               \
    _Pragma("unroll")                                                          \
    for (int e = 0; e < 8; ++e) { int wq = w0t_ + e;                           \
      wvx_[e] = wq >= 56 ? wq - 56 : wq; }                                     \
    if (hf == 0) {                                                             \
      _Pragma("unroll")                                                        \
      for (int k = 0; k < 4; ++k) {                                            \
        __attribute__((aligned(16))) u16 v_[8];                                \
        _Pragma("unroll")                                                      \
        for (int e = 0; e < 8; ++e)                                            \
          v_[e] = ((unsigned)(wvx_[e] + k - 3) < 56u) ? (Wd)[e + k + 5] : (u16)0; \
        *(uint4*)&(BsD)[(jl * 8 + k) * 64 + (pc ^ k) * 8] = *(const uint4*)v_; \
      }                                                                        \
    } else {                                                                   \
      _Pragma("unroll")                                                        \
      for (int k = 4; k < 7; ++k) {                                            \
        __attribute__((aligned(16))) u16 v_[8];                                \
        _Pragma("unroll")                                                      \
        for (int e = 0; e < 8; ++e)                                            \
          v_[e] = ((unsigned)(wvx_[e] + k - 3) < 56u) ? (Wd)[e + k + 5] : (u16)0; \
        *(uint4*)&(BsD)[(jl * 8 + k) * 64 + (pc ^ k) * 8] = *(const uint4*)v_; \
      }                                                                        \
      *(uint4*)&(BsD)[(jl * 8 + 7) * 64 + (pc ^ 7) * 8] = *(const uint4*)(Ar); \
    } } while (0)

#define MF1(AsS, BsS) do {                                                     \
    __builtin_amdgcn_s_setprio(1);                                             \
    _Pragma("unroll")                                                          \
    for (int kk = 0; kk < 2; ++kk) {                                           \
      const int phys = ((kk * 4 + quad) ^ (lm & 7)) * 8;                       \
      bf16x8 af[4], bv[4];                                                     \
      _Pragma("unroll")                                                        \
      for (int mi = 0; mi < 4; ++mi)                                           \
        af[mi] = *(const bf16x8*)&(AsS)[(wm * 64 + mi * 16 + lm) * 64 + phys]; \
      _Pragma("unroll")                                                        \
      for (int ni = 0; ni < 4; ++ni)                                           \
        bv[ni] = *(const bf16x8*)&(BsS)[(wn * 64 + ni * 16 + lm) * 64 + phys]; \
      _Pragma("unroll")                                                        \
      for (int mi = 0; mi < 4; ++mi)                                           \
        _Pragma("unroll")                                                      \
        for (int ni = 0; ni < 4; ++ni)                                         \
          acc[mi][ni] = __builtin_amdgcn_mfma_f32_16x16x32_bf16(               \
              af[mi], bv[ni], acc[mi][ni], 0, 0, 0);                           \
    }                                                                          \
    __builtin_amdgcn_s_setprio(0); } while (0)

// One uniform region: issue DMA(it+1), build B(it+1) from regs (compiler
// auto-waits their loads), prefetch sources(it+2), MFMA current, then drain
// ONLY the DMA (vmcnt(4) leaves the 4 PF loads in flight) and barrier.
#define REGION1(bAr, bWd, pAr, pWd, AsC, BsC, AsN, BsN, itn) do {              \
    DMA1(AsN, min((itn) + 1, itL));                                            \
    MEMFENCE();                                                                \
    BUILD1(bAr, bWd, BsN, min((itn) + 1, itL));                                \
    PF1(pAr, pWd, min((itn) + 2, itL));                                        \
    MF1(AsC, BsC);                                                             \
    asm volatile("s_waitcnt vmcnt(4) lgkmcnt(0)" ::: "memory");                \
    __builtin_amdgcn_s_barrier();                                              \
    MEMFENCE();                                                                \
    __builtin_amdgcn_sched_barrier(0); } while (0)

  // ---- prologue ----
  PF1(ArE, WdE, it0);                  // 4 loads: sources(it0)
  DMA1(As0, it0);                      // 4 loads: A tile it0
  PF1(ArO, WdO, min(it0 + 1, itL));    // 4 loads: sources(it0+1)
  BUILD1(ArE, WdE, Bs0, it0);          // compiler auto-waits the ArE/WdE loads
  asm volatile("s_waitcnt vmcnt(4) lgkmcnt(0)" ::: "memory");  // DMA0 done
  __builtin_amdgcn_s_barrier();
  MEMFENCE();
  __builtin_amdgcn_sched_barrier(0);

  // ---- main: regions alternate buffers; it0 even so parity is stable ----
  int it = it0;
  while (true) {
    REGION1(ArO, WdO, ArE, WdE, As0, Bs0, As1, Bs1, it); ++it;   // even
    if (it >= it1) break;
    REGION1(ArE, WdE, ArO, WdO, As1, Bs1, As0, Bs0, it); ++it;   // odd
    if (it >= it1) break;
  }

#undef DMA1
#undef PF1
#undef BUILD1
#undef MF1
#undef REGION1

  // fp32 partial store; C/D layout: col = lane&15, row = quad*4 + reg
  float* Cb = Cp + ((long)ks * NB + nb) * (long)CC * CKP;
#pragma unroll
  for (int mi = 0; mi < 4; ++mi)
#pragma unroll
    for (int ni = 0; ni < 4; ++ni) {
      int rb = m0 + wm * 64 + mi * 16 + quad * 4;
      int cg = n0 + wn * 64 + ni * 16 + lm;
#pragma unroll
      for (int r = 0; r < 4; ++r)
        Cb[(long)(rb + r) * CKP + cg] = acc[mi][ni][r];
    }
}

// ---------------------------------------------------------------------------
// reduce1: per thread = one j-group (8 cols).  Sums KS1 partials,
// forms t7[jk] = (G - H_k)/56 for k<7 (fp32 subtract), and writes
// S7 = sum_k t7[jk] into slot 7 (consumed by gemm2f's pad MFMA slots).
// grid = NB*CC*CKP/8/256 = 2048
// ---------------------------------------------------------------------------
__global__ void reduce1(const float* __restrict__ p1, u16* __restrict__ t7) {
  const int g = blockIdx.x * 256 + threadIdx.x;   // j-group over NB*CC*CKP/8
  const long S = (long)NB * CC * CKP;             // elements per partial
  const long base = (long)g * 8;
  float a[8];
#pragma unroll
  for (int e = 0; e < 8; ++e) a[e] = 0.0f;
#pragma unroll
  for (int ks = 0; ks < KS1; ++ks) {
    float4 lo = *(const float4*)&p1[ks * S + base];
    float4 hi = *(const float4*)&p1[ks * S + base + 4];
    a[0] += lo.x; a[1] += lo.y; a[2] += lo.z; a[3] += lo.w;
    a[4] += hi.x; a[5] += hi.y; a[6] += hi.z; a[7] += hi.w;
  }
  const float s = 1.0f / 56.0f;
  const float G = a[7];
  __attribute__((aligned(16))) u16 o[8];
  float s7 = 0.0f;
#pragma unroll
  for (int k = 0; k < 7; ++k) {
    float v = (G - a[k]) * s;
    s7 += v;
    o[k] = f2bf(v);
  }
  o[7] = f2bf(s7);
  *(uint4*)&t7[base] = *(const uint4*)o;
}

// ---------------------------------------------------------------------------
// gemm2f (R11): fused NT GEMM, 128x64 tile, BK=64, NO split-K.
//   out[i][p] = s2 * ( sum_{j,k<7} t7[i][jk]*tap[j,k,p]  +  S7[i][j]*xb[j][p] )
// xb term rides in pad slots (A col j*8+7 = S7, B row j*8+7 = raw xb).
// Counted-vmcnt pipeline: manual s_waitcnt vmcnt(16) drains only this
// region's 4 A-DMA ops; the 16 scalar B-source prefetch loads (it+2) cross
// the barrier with a full region of cover.  grid = (2, 49, NB)
// ---------------------------------------------------------------------------
__global__ __launch_bounds__(256)
void gemm2f(const u16* __restrict__ A, const u16* __restrict__ xb,
            const u16* __restrict__ t1b, float* __restrict__ out) {
  __shared__ u16 As0[128 * 64], As1[128 * 64];
  __shared__ u16 Bs0[64 * 64], Bs1[64 * 64];

  const int nb = blockIdx.z;
  const u16* Ab  = A   + (long)nb * CC * CKP;
  const u16* xbn = xb  + (long)nb * CC * HW;
  const u16* t1n = t1b + (long)nb * CC * HW;
  const int m0 = blockIdx.x * 128, n0 = blockIdx.y * 64;
  const int t = threadIdx.x;
  const int lane = t & 63, wave = t >> 6;
  const int wm = wave & 1, wn = wave >> 1;        // 2(m) x 2(n of 32)
  const int lm = lane & 15, quad = lane >> 4;

  // B-gen mapping: pr = p-row, jg -> 2 channels per thread per iter
  const int pr = t & 63, jg = t >> 6;
  const int p  = n0 + pr;
  const int h  = p / WW, w = p - h * WW;
  const int h2 = (h + HH - 1) % HH;               // roll +1 on h
  const int w2 = (w + 1) % WW;                    // roll -1 on w
  const int swz = pr & 7;

  // hoisted per-k tap offsets + masks (iter-invariant, depend on p only)
  int toff[7], tmsk[7];
#pragma unroll
  for (int k = 0; k < 7; ++k) {
    int ww = w2 + k - 3;
    int wc = ww < 0 ? 0 : (ww > 55 ? 55 : ww);    // clamped, in-bounds
    toff[k] = h2 * WW + wc;
    tmsk[k] = ((unsigned)ww < 56u);
  }

  f32x4 acc[4][2];
#pragma unroll
  for (int a = 0; a < 4; ++a)
#pragma unroll
    for (int b = 0; b < 2; ++b) acc[a][b] = (f32x4)0.0f;

  int rowc[4], colc[4];
#pragma unroll
  for (int ci = 0; ci < 4; ++ci) {
    int c = t + ci * 256;
    rowc[ci] = c >> 3;
    colc[ci] = ((c & 7) ^ (rowc[ci] & 7)) * 8;
  }

  // two named prefetch register sets (even/odd iterations) — static indexing
  u16 trE[2][7], xrE[2], trO[2][7], xrO[2];

#define DMA2(AsD, itn) do { const int k0_ = (itn) * 64;                        \
    _Pragma("unroll")                                                          \
    for (int ci = 0; ci < 4; ++ci)                                             \
      lds_load16(Ab + (long)(m0 + rowc[ci]) * CKP + k0_ + colc[ci],            \
                 &AsD[(t + ci * 256) * 8]); } while (0)

#define PF2(tr, xr, itn) do {                                                  \
    _Pragma("unroll")                                                          \
    for (int jj = 0; jj < 2; ++jj) {                                           \
      const int jch = (itn) * 8 + jg * 2 + jj;                                 \
      const int jmm = (jch + CC - 1) & (CC - 1);                               \
      const u16* trow = t1n + (long)jmm * HW;                                  \
      _Pragma("unroll")                                                        \
      for (int k = 0; k < 7; ++k) (tr)[jj][k] = trow[toff[k]];                 \
      (xr)[jj] = xbn[(long)jch * HW + p]; } } while (0)

#define BUILD2(tr, xr, BsD) do {                                               \
    _Pragma("unroll")                                                          \
    for (int jj = 0; jj < 2; ++jj) {                                           \
      __attribute__((aligned(16))) u16 v_[8];                                  \
      _Pragma("unroll")                                                        \
      for (int k = 0; k < 7; ++k) v_[k] = tmsk[k] ? (tr)[jj][k] : (u16)0;      \
      v_[7] = (xr)[jj];                                                        \
      *(uint4*)&(BsD)[pr * 64 + (((jg * 2 + jj) ^ swz) * 8)] =                 \
          *(const uint4*)v_; } } while (0)

#define MF2(AsS, BsS) do {                                                     \
    __builtin_amdgcn_s_setprio(1);                                             \
    _Pragma("unroll")                                                          \
    for (int kk = 0; kk < 2; ++kk) {                                           \
      const int phys = ((kk * 4 + quad) ^ (lm & 7)) * 8;                       \
      bf16x8 af[4], bv[2];                                                     \
      _Pragma("unroll")                                                        \
      for (int mi = 0; mi < 4; ++mi)                                           \
        af[mi] = *(const bf16x8*)&(AsS)[(wm * 64 + mi * 16 + lm) * 64 + phys]; \
      _Pragma("unroll")                                                        \
      for (int ni = 0; ni < 2; ++ni)                                           \
        bv[ni] = *(const bf16x8*)&(BsS)[(wn * 32 + ni * 16 + lm) * 64 + phys]; \
      _Pragma("unroll")                                                        \
      for (int mi = 0; mi < 4; ++mi)                                           \
        _Pragma("unroll")                                                      \
        for (int ni = 0; ni < 2; ++ni)                                         \
          acc[mi][ni] = __builtin_amdgcn_mfma_f32_16x16x32_bf16(               \
              af[mi], bv[ni], acc[mi][ni], 0, 0, 0);                           \
    }                                                                          \
    __builtin_amdgcn_s_setprio(0); } while (0)

#define REGION2(bTr, bXr, pTr, pXr, AsC, BsC, AsN, BsN, itn) do {              \
    DMA2(AsN, min((itn) + 1, 31));                                             \
    MEMFENCE();                                                                \
    BUILD2(bTr, bXr, BsN);                                                     \
    PF2(pTr, pXr, min((itn) + 2, 31));                                         \
    MF2(AsC, BsC);                                                             \
    asm volatile("s_waitcnt vmcnt(16) lgkmcnt(0)" ::: "memory");               \
    __builtin_amdgcn_s_barrier();                                              \
    MEMFENCE();                                                                \
    __builtin_amdgcn_sched_barrier(0); } while (0)

  // ---- prologue ----
  PF2(trE, xrE, 0);                    // 16 loads: sources(0)
  DMA2(As0, 0);                        // 4 loads: A tile 0
  PF2(trO, xrO, 1);                    // 16 loads: sources(1)
  BUILD2(trE, xrE, Bs0);               // compiler auto-waits trE/xrE loads
  asm volatile("s_waitcnt vmcnt(16) lgkmcnt(0)" ::: "memory");  // DMA0 done
  __builtin_amdgcn_s_barrier();
  MEMFENCE();
  __builtin_amdgcn_sched_barrier(0);

  // ---- main: 32 iterations, even count -> clean pair loop ----
  for (int m = 0; m < 16; ++m) {
    const int itE = 2 * m;
    REGION2(trO, xrO, trE, xrE, As0, Bs0, As1, Bs1, itE);
    REGION2(trE, xrE, trO, xrO, As1, Bs1, As0, Bs0, itE + 1);
  }

#undef DMA2
#undef PF2
#undef BUILD2
#undef MF2
#undef REGION2

  const float s2 = 0.023622783f;                  // 1/sqrt(1792)
  float* Ob = out + (long)nb * CC * HW;
#pragma unroll
  for (int mi = 0; mi < 4; ++mi)
#pragma unroll
    for (int ni = 0; ni < 2; ++ni) {
      int rb = m0 + wm * 64 + mi * 16 + quad * 4;
      int cg = n0 + wn * 32 + ni * 16 + lm;       // < 3136 always (49*64)
#pragma unroll
      for (int r = 0; r < 4; ++r)
        Ob[(long)(rb + r) * HW + cg] = acc[mi][ni][r] * s2;
    }
}

// ---------------------------------------------------------------------------
// Pipeline: pass1 -> gemm1f -> reduce1 -> gemm2f(-> d_out).  ~68 MB footprint.
// ---------------------------------------------------------------------------
extern "C" void kernel_launch(void* const* d_in, const int* in_sizes, int n_in,
                              void* d_out, int out_size, void* d_ws, size_t ws_size,
                              hipStream_t stream) {
  const float* x   = (const float*)d_in[0];   // (8,256,56,56)
  const float* p1w = (const float*)d_in[1];   // (1,256,56,56)

  char* ws = (char*)d_ws;
  size_t o = 0;
  u16* xb  = (u16*)(ws + o); o += (size_t)NB * CC * HW * 2;          //  12.8 MB
  u16* t1b = (u16*)(ws + o); o += (size_t)NB * CC * HW * 2;          //  12.8 MB
  u16* t7  = (u16*)(ws + o); o += (size_t)NB * CC * CKP * 2;         //   8.4 MB
  float* p1 = (float*)(ws + o); o += (size_t)KS1 * NB * CC * CKP * 4; // 33.5 MB

  pass1<<<NB * CC * HW / 4 / 256, 256, 0, stream>>>(x, p1w, t1b, xb);
  gemm1f<<<dim3(2, 16, NB * KS1), 256, 0, stream>>>(xb, t1b, p1);
  reduce1<<<NB * CC * CKP / 8 / 256, 256, 0, stream>>>(p1, t7);
  gemm2f<<<dim3(2, 49, NB), 256, 0, stream>>>(t7, xb, t1b, (float*)d_out);
}

// Round 4
// 216.447 us; speedup vs baseline: 1.1852x; 1.1852x over previous
//
#include <hip/hip_runtime.h>

typedef unsigned short u16;
typedef __bf16 bf16x8 __attribute__((ext_vector_type(8)));
typedef float f32x4 __attribute__((ext_vector_type(4)));

#define HH  56
#define WW  56
#define HW  3136      // 56*56
#define CC  256
#define NB  8
#define CKP 2048      // c*7 padded to c*8: channel j's taps = cols j*8..j*8+7
#define KS1 4         // split-K factor GEMM1 (49 iters -> 12/12/12/13)

// round-to-nearest-even fp32 -> bf16 (bit pattern) — for non-hot paths
__device__ __forceinline__ u16 f2bf(float f) {
  unsigned int u = __float_as_uint(f);
  u += 0x7fffu + ((u >> 16) & 1u);
  return (u16)(u >> 16);
}
__device__ __forceinline__ float bf2f(u16 v) {
  return __uint_as_float((unsigned)v << 16);
}

// async global->LDS DMA, 16B per lane; dest = wave-uniform base + lane*16
__device__ __forceinline__ void lds_load16(const void* g, void* l) {
  __builtin_amdgcn_global_load_lds(
      (const __attribute__((address_space(1))) void*)g,
      (__attribute__((address_space(3))) void*)l, 16, 0, 0);
}

// ---------------------------------------------------------------------------
// pass1: t1b = bf16(p1w * x), xb = bf16(x).  Fully coalesced float4 reads.
// grid = N*C*HW/4/256 = 6272
// ---------------------------------------------------------------------------
__global__ void pass1(const float* __restrict__ x, const float* __restrict__ p1w,
                      u16* __restrict__ t1b, u16* __restrict__ xb) {
  int i = blockIdx.x * 256 + threadIdx.x;        // over N*C*HW/4
  int cw = i % (CC * HW / 4);                    // p1w broadcast over n
  float4 xv = ((const float4*)x)[i];
  float4 wv = ((const float4*)p1w)[cw];
  uint2 xo = make_uint2((unsigned)f2bf(xv.x) | ((unsigned)f2bf(xv.y) << 16),
                        (unsigned)f2bf(xv.z) | ((unsigned)f2bf(xv.w) << 16));
  ((uint2*)xb)[i] = xo;
  uint2 to = make_uint2((unsigned)f2bf(xv.x * wv.x) | ((unsigned)f2bf(xv.y * wv.y) << 16),
                        (unsigned)f2bf(xv.z * wv.z) | ((unsigned)f2bf(xv.w * wv.w) << 16));
  ((uint2*)t1b)[i] = to;
}

// ---------------------------------------------------------------------------
// gemm1f (R12): fused NT GEMM (split-K=4), 64x128 tile, BK=64.
// TLP-first: BM=64 doubles the grid (2048 blocks = 8/CU desired, 5-6/CU
// resident at 24 KB LDS) — both GEMMs are latency-bound and time tracks
// blocks/CU (R10/R11 evidence).  Proven R9 2-barrier schedule, plain
// __syncthreads, select-only B-gen.
//   B rows j*8+k (k<7) = masked taps of t2[j]; row j*8+7 = t1[j] (G-row).
// Writes fp32 partials Cp[ks][nb][256][CKP].  grid = (4, 16, NB*KS1)
// ---------------------------------------------------------------------------
__global__ __launch_bounds__(256, 5)
void gemm1f(const u16* __restrict__ A, const u16* __restrict__ t1b,
            float* __restrict__ Cp) {
  __shared__ u16 As[64 * 64];        //  8 KB
  __shared__ u16 Bs[128 * 64];       // 16 KB

  const int z = blockIdx.z, nb = z / KS1, ks = z % KS1;
  const int it0 = 49 * ks / KS1, it1 = 49 * (ks + 1) / KS1;
  const u16* Ab  = A   + (long)nb * CC * HW;
  const u16* t1n = t1b + (long)nb * CC * HW;
  const int m0 = blockIdx.x * 64, n0 = blockIdx.y * 128;
  const int jb = blockIdx.y * 16;                 // first channel of tile
  const int t = threadIdx.x;
  const int lane = t & 63, wave = t >> 6;
  const int wm = wave & 1, wn = wave >> 1;        // 2(m of 32) x 2(n of 64)
  const int lm = lane & 15, quad = lane >> 4;

  // B-gen mapping
  const int jl = (t >> 3) & 15, pc = t & 7, hf = t >> 7;   // hf wave-uniform
  const int j  = jb + jl;
  const int jm = (j + CC - 1) & (CC - 1);
  const u16* arow = t1n + (long)j  * HW;
  const u16* wrow = t1n + (long)jm * HW;

  f32x4 acc[2][4];
#pragma unroll
  for (int a = 0; a < 2; ++a)
#pragma unroll
    for (int b = 0; b < 4; ++b) acc[a][b] = (f32x4)0.0f;

  // A staging geometry: 512 chunks of 16B, 2 per thread, XOR swizzle
  int rowc[2], colc[2];
#pragma unroll
  for (int ci = 0; ci < 2; ++ci) {
    int c = t + ci * 256;
    rowc[ci] = c >> 3;
    colc[ci] = ((c & 7) ^ (rowc[ci] & 7)) * 8;
  }

  for (int it = it0; it < it1; ++it) {
    const int k0 = it * 64;
#pragma unroll
    for (int ci = 0; ci < 2; ++ci)
      lds_load16(Ab + (long)(m0 + rowc[ci]) * HW + k0 + colc[ci],
                 &As[(t + ci * 256) * 8]);

    // ---- B-gen: 8 p-values (p8..p8+7), rows jl*8+k. Pure u16 selects. ----
    {
      const int p8 = k0 + pc * 8;
      __attribute__((aligned(16))) u16 Ar[8];
      __attribute__((aligned(16))) u16 Wd[24];     // window = flat [p8-8, p8+16)
      *(uint4*)Ar = *(const uint4*)&arow[p8];
#pragma unroll
      for (int L = 0; L < 3; ++L) {
        int ad = p8 - 8 + L * 8;
        ad = ad < 0 ? 0 : (ad > HW - 8 ? HW - 8 : ad);  // garbage only at masked idx
        *(uint4*)&Wd[L * 8] = *(const uint4*)&wrow[ad];
      }
      const int w0t = p8 % 56;
      int wv[8];
#pragma unroll
      for (int e = 0; e < 8; ++e) { int w = w0t + e; wv[e] = w >= 56 ? w - 56 : w; }
      if (hf == 0) {                           // k = 0..3
#pragma unroll
        for (int k = 0; k < 4; ++k) {
          __attribute__((aligned(16))) u16 v[8];
#pragma unroll
          for (int e = 0; e < 8; ++e)
            v[e] = ((unsigned)(wv[e] + k - 3) < 56u) ? Wd[e + k + 5] : (u16)0;
          *(uint4*)&Bs[(jl * 8 + k) * 64 + (pc ^ k) * 8] = *(const uint4*)v;
        }
      } else {                                 // k = 4..6 + G-row (slot 7)
#pragma unroll
        for (int k = 4; k < 7; ++k) {
          __attribute__((aligned(16))) u16 v[8];
#pragma unroll
          for (int e = 0; e < 8; ++e)
            v[e] = ((unsigned)(wv[e] + k - 3) < 56u) ? Wd[e + k + 5] : (u16)0;
          *(uint4*)&Bs[(jl * 8 + k) * 64 + (pc ^ k) * 8] = *(const uint4*)v;
        }
        // slot 7 = t1[j] row -> produces G[i][j] in output col j*8+7
        *(uint4*)&Bs[(jl * 8 + 7) * 64 + (pc ^ 7) * 8] = *(const uint4*)Ar;
      }
    }
    __syncthreads();
#pragma unroll
    for (int kk = 0; kk < 2; ++kk) {
      const int phys = ((kk * 4 + quad) ^ (lm & 7)) * 8;
      bf16x8 af[2], bv[4];
#pragma unroll
      for (int mi = 0; mi < 2; ++mi)
        af[mi] = *(const bf16x8*)&As[(wm * 32 + mi * 16 + lm) * 64 + phys];
#pragma unroll
      for (int ni = 0; ni < 4; ++ni)
        bv[ni] = *(const bf16x8*)&Bs[(wn * 64 + ni * 16 + lm) * 64 + phys];
#pragma unroll
      for (int mi = 0; mi < 2; ++mi)
#pragma unroll
        for (int ni = 0; ni < 4; ++ni)
          acc[mi][ni] = __builtin_amdgcn_mfma_f32_16x16x32_bf16(
              af[mi], bv[ni], acc[mi][ni], 0, 0, 0);
    }
    __syncthreads();
  }

  // fp32 partial store; C/D layout: col = lane&15, row = quad*4 + reg
  float* Cb = Cp + ((long)ks * NB + nb) * (long)CC * CKP;
#pragma unroll
  for (int mi = 0; mi < 2; ++mi)
#pragma unroll
    for (int ni = 0; ni < 4; ++ni) {
      int rb = m0 + wm * 32 + mi * 16 + quad * 4;
      int cg = n0 + wn * 64 + ni * 16 + lm;
#pragma unroll
      for (int r = 0; r < 4; ++r)
        Cb[(long)(rb + r) * CKP + cg] = acc[mi][ni][r];
    }
}

// ---------------------------------------------------------------------------
// reduce1: per thread = one j-group (8 cols).  Sums KS1 partials,
// forms t7[jk] = (G - H_k)/56 for k<7 (fp32 subtract), and writes
// S7 = sum_k t7[jk] into slot 7 (consumed by gemm2f's pad MFMA slots).
// grid = NB*CC*CKP/8/256 = 2048
// ---------------------------------------------------------------------------
__global__ void reduce1(const float* __restrict__ p1, u16* __restrict__ t7) {
  const int g = blockIdx.x * 256 + threadIdx.x;   // j-group over NB*CC*CKP/8
  const long S = (long)NB * CC * CKP;             // elements per partial
  const long base = (long)g * 8;
  float a[8];
#pragma unroll
  for (int e = 0; e < 8; ++e) a[e] = 0.0f;
#pragma unroll
  for (int ks = 0; ks < KS1; ++ks) {
    float4 lo = *(const float4*)&p1[ks * S + base];
    float4 hi = *(const float4*)&p1[ks * S + base + 4];
    a[0] += lo.x; a[1] += lo.y; a[2] += lo.z; a[3] += lo.w;
    a[4] += hi.x; a[5] += hi.y; a[6] += hi.z; a[7] += hi.w;
  }
  const float s = 1.0f / 56.0f;
  const float G = a[7];
  __attribute__((aligned(16))) u16 o[8];
  float s7 = 0.0f;
#pragma unroll
  for (int k = 0; k < 7; ++k) {
    float v = (G - a[k]) * s;
    s7 += v;
    o[k] = f2bf(v);
  }
  o[7] = f2bf(s7);
  *(uint4*)&t7[base] = *(const uint4*)o;
}

// ---------------------------------------------------------------------------
// gemm2f (R12): fused NT GEMM, 64x64 tile, BK=64, NO split-K.
//   out[i][p] = s2 * ( sum_{j,k<7} t7[i][jk]*tap[j,k,p]  +  S7[i][j]*xb[j][p] )
// xb term rides in pad slots (A col j*8+7 = S7, B row j*8+7 = raw xb).
// TLP-first: BM=64 -> grid 1568 blocks = 6.1/CU (vs 3.06 at BM=128); LDS
// 16 KB.  R9 2-barrier schedule, inline B-source loads, select-only B-gen,
// hoisted tap offsets/masks.  grid = (4, 49, NB)
// ---------------------------------------------------------------------------
__global__ __launch_bounds__(256, 6)
void gemm2f(const u16* __restrict__ A, const u16* __restrict__ xb,
            const u16* __restrict__ t1b, float* __restrict__ out) {
  __shared__ u16 As[64 * 64];        // 8 KB
  __shared__ u16 Bs[64 * 64];        // 8 KB

  const int nb = blockIdx.z;
  const u16* Ab  = A   + (long)nb * CC * CKP;
  const u16* xbn = xb  + (long)nb * CC * HW;
  const u16* t1n = t1b + (long)nb * CC * HW;
  const int m0 = blockIdx.x * 64, n0 = blockIdx.y * 64;
  const int t = threadIdx.x;
  const int lane = t & 63, wave = t >> 6;
  const int wm = wave & 1, wn = wave >> 1;        // 2(m of 32) x 2(n of 32)
  const int lm = lane & 15, quad = lane >> 4;

  // B-gen mapping: pr = p-row, jg -> 2 channels per thread per iter
  const int pr = t & 63, jg = t >> 6;
  const int p  = n0 + pr;
  const int h  = p / WW, w = p - h * WW;
  const int h2 = (h + HH - 1) % HH;               // roll +1 on h
  const int w2 = (w + 1) % WW;                    // roll -1 on w
  const int swz = pr & 7;

  // hoisted per-k tap offsets + masks (iter-invariant, depend on p only)
  int toff[7], tmsk[7];
#pragma unroll
  for (int k = 0; k < 7; ++k) {
    int ww = w2 + k - 3;
    int wc = ww < 0 ? 0 : (ww > 55 ? 55 : ww);    // clamped, in-bounds
    toff[k] = h2 * WW + wc;
    tmsk[k] = ((unsigned)ww < 56u);
  }

  f32x4 acc[2][2];
#pragma unroll
  for (int a = 0; a < 2; ++a)
#pragma unroll
    for (int b = 0; b < 2; ++b) acc[a][b] = (f32x4)0.0f;

  // A staging geometry: 512 chunks of 16B, 2 per thread, XOR swizzle
  int rowc[2], colc[2];
#pragma unroll
  for (int ci = 0; ci < 2; ++ci) {
    int c = t + ci * 256;
    rowc[ci] = c >> 3;
    colc[ci] = ((c & 7) ^ (rowc[ci] & 7)) * 8;
  }

  for (int it = 0; it < 32; ++it) {
    const int k0 = it * 64;
#pragma unroll
    for (int ci = 0; ci < 2; ++ci)
      lds_load16(Ab + (long)(m0 + rowc[ci]) * CKP + k0 + colc[ci],
                 &As[(t + ci * 256) * 8]);

    // ---- B-gen: 2 channels, inline loads, pure u16 selects ----
#pragma unroll
    for (int jj = 0; jj < 2; ++jj) {
      const int jch = it * 8 + jg * 2 + jj;
      const int jmm = (jch + CC - 1) & (CC - 1);
      const u16* trow = t1n + (long)jmm * HW;
      __attribute__((aligned(16))) u16 v[8];
#pragma unroll
      for (int k = 0; k < 7; ++k) {
        u16 tv = trow[toff[k]];
        v[k] = tmsk[k] ? tv : (u16)0;
      }
      v[7] = xbn[(long)jch * HW + p];             // pad slot carries xb term
      *(uint4*)&Bs[pr * 64 + (((jg * 2 + jj) ^ swz) * 8)] = *(const uint4*)v;
    }
    __syncthreads();
#pragma unroll
    for (int kk = 0; kk < 2; ++kk) {
      const int phys = ((kk * 4 + quad) ^ (lm & 7)) * 8;
      bf16x8 af[2], bv[2];
#pragma unroll
      for (int mi = 0; mi < 2; ++mi)
        af[mi] = *(const bf16x8*)&As[(wm * 32 + mi * 16 + lm) * 64 + phys];
#pragma unroll
      for (int ni = 0; ni < 2; ++ni)
        bv[ni] = *(const bf16x8*)&Bs[(wn * 32 + ni * 16 + lm) * 64 + phys];
#pragma unroll
      for (int mi = 0; mi < 2; ++mi)
#pragma unroll
        for (int ni = 0; ni < 2; ++ni)
          acc[mi][ni] = __builtin_amdgcn_mfma_f32_16x16x32_bf16(
              af[mi], bv[ni], acc[mi][ni], 0, 0, 0);
    }
    __syncthreads();
  }

  const float s2 = 0.023622783f;                  // 1/sqrt(1792)
  float* Ob = out + (long)nb * CC * HW;
#pragma unroll
  for (int mi = 0; mi < 2; ++mi)
#pragma unroll
    for (int ni = 0; ni < 2; ++ni) {
      int rb = m0 + wm * 32 + mi * 16 + quad * 4;
      int cg = n0 + wn * 32 + ni * 16 + lm;       // < 3136 always (49*64)
#pragma unroll
      for (int r = 0; r < 4; ++r)
        Ob[(long)(rb + r) * HW + cg] = acc[mi][ni][r] * s2;
    }
}

// ---------------------------------------------------------------------------
// Pipeline: pass1 -> gemm1f -> reduce1 -> gemm2f(-> d_out).  ~101 MB footprint.
// ---------------------------------------------------------------------------
extern "C" void kernel_launch(void* const* d_in, const int* in_sizes, int n_in,
                              void* d_out, int out_size, void* d_ws, size_t ws_size,
                              hipStream_t stream) {
  const float* x   = (const float*)d_in[0];   // (8,256,56,56)
  const float* p1w = (const float*)d_in[1];   // (1,256,56,56)

  char* ws = (char*)d_ws;
  size_t o = 0;
  u16* xb  = (u16*)(ws + o); o += (size_t)NB * CC * HW * 2;          //  12.8 MB
  u16* t1b = (u16*)(ws + o); o += (size_t)NB * CC * HW * 2;          //  12.8 MB
  u16* t7  = (u16*)(ws + o); o += (size_t)NB * CC * CKP * 2;         //   8.4 MB
  float* p1 = (float*)(ws + o); o += (size_t)KS1 * NB * CC * CKP * 4; // 67.1 MB

  pass1<<<NB * CC * HW / 4 / 256, 256, 0, stream>>>(x, p1w, t1b, xb);
  gemm1f<<<dim3(4, 16, NB * KS1), 256, 0, stream>>>(xb, t1b, p1);
  reduce1<<<NB * CC * CKP / 8 / 256, 256, 0, stream>>>(p1, t7);
  gemm2f<<<dim3(4, 49, NB), 256, 0, stream>>>(t7, xb, t1b, (float*)d_out);
}

// Round 5
// 185.596 us; speedup vs baseline: 1.3823x; 1.1662x over previous
//
#include <hip/hip_runtime.h>

typedef unsigned short u16;
typedef __bf16 bf16x8 __attribute__((ext_vector_type(8)));
typedef float f32x4 __attribute__((ext_vector_type(4)));

#define HH  56
#define WW  56
#define HW  3136      // 56*56
#define CC  256
#define NB  8
#define CKP 2048      // c*7 padded to c*8: channel j's taps = cols j*8..j*8+7
#define KS1 4         // split-K factor GEMM1 (49 iters -> 12/12/12/13)

// round-to-nearest-even fp32 -> bf16 (bit pattern) — for non-hot paths
__device__ __forceinline__ u16 f2bf(float f) {
  unsigned int u = __float_as_uint(f);
  u += 0x7fffu + ((u >> 16) & 1u);
  return (u16)(u >> 16);
}
__device__ __forceinline__ float bf2f(u16 v) {
  return __uint_as_float((unsigned)v << 16);
}

// async global->LDS DMA, 16B per lane; dest = wave-uniform base + lane*16
__device__ __forceinline__ void lds_load16(const void* g, void* l) {
  __builtin_amdgcn_global_load_lds(
      (const __attribute__((address_space(1))) void*)g,
      (__attribute__((address_space(3))) void*)l, 16, 0, 0);
}

// ---------------------------------------------------------------------------
// pass1: t1b = bf16(p1w * x), xb = bf16(x).  Fully coalesced float4 reads.
// grid = N*C*HW/4/256 = 6272
// ---------------------------------------------------------------------------
__global__ void pass1(const float* __restrict__ x, const float* __restrict__ p1w,
                      u16* __restrict__ t1b, u16* __restrict__ xb) {
  int i = blockIdx.x * 256 + threadIdx.x;        // over N*C*HW/4
  int cw = i % (CC * HW / 4);                    // p1w broadcast over n
  float4 xv = ((const float4*)x)[i];
  float4 wv = ((const float4*)p1w)[cw];
  uint2 xo = make_uint2((unsigned)f2bf(xv.x) | ((unsigned)f2bf(xv.y) << 16),
                        (unsigned)f2bf(xv.z) | ((unsigned)f2bf(xv.w) << 16));
  ((uint2*)xb)[i] = xo;
  uint2 to = make_uint2((unsigned)f2bf(xv.x * wv.x) | ((unsigned)f2bf(xv.y * wv.y) << 16),
                        (unsigned)f2bf(xv.z * wv.z) | ((unsigned)f2bf(xv.w * wv.w) << 16));
  ((uint2*)t1b)[i] = to;
}

// ---------------------------------------------------------------------------
// gemm1f (R13): fused NT GEMM (split-K=4), 128x128 tile, BK=64.
// XCD-PINNED: flat 1-D grid, nb = blockIdx.x & 7 -> with round-robin
// dispatch all blocks of batch nb land on XCD nb.  Per-XCD working set
// (xb 1.6 MB + t1b 1.6 MB per batch) becomes L2-resident instead of all
// 8 batches thrashing every XCD's 4 MB L2 through Infinity Cache.
// Proven R9 2-barrier schedule, select-only B-gen.
//   B rows j*8+k (k<7) = masked taps of t2[j]; row j*8+7 = t1[j] (G-row).
// Writes fp32 partials Cp[ks][nb][256][CKP].  grid = 1024 flat
// ---------------------------------------------------------------------------
__global__ __launch_bounds__(256)
void gemm1f(const u16* __restrict__ A, const u16* __restrict__ t1b,
            float* __restrict__ Cp) {
  __shared__ u16 As[128 * 64];
  __shared__ u16 Bs[128 * 64];

  // flat block index -> (nb | ks | m0b | n0b), nb fastest => XCD-pinned
  const int bi = blockIdx.x;
  const int nb = bi & 7;
  const int r  = bi >> 3;          // 0..127
  const int ks = r & 3;
  const int r2 = r >> 2;           // 0..31
  const int m0b = r2 & 1;
  const int n0b = r2 >> 1;         // 0..15

  const int it0 = 49 * ks / KS1, it1 = 49 * (ks + 1) / KS1;
  const u16* Ab  = A   + (long)nb * CC * HW;
  const u16* t1n = t1b + (long)nb * CC * HW;
  const int m0 = m0b * 128, n0 = n0b * 128;
  const int jb = n0b * 16;                        // first channel of tile
  const int t = threadIdx.x;
  const int lane = t & 63, wave = t >> 6;
  const int wm = wave & 1, wn = wave >> 1;        // 2x2 waves, 64x64 each
  const int lm = lane & 15, quad = lane >> 4;

  // B-gen mapping
  const int jl = (t >> 3) & 15, pc = t & 7, hf = t >> 7;   // hf wave-uniform
  const int j  = jb + jl;
  const int jm = (j + CC - 1) & (CC - 1);
  const u16* arow = t1n + (long)j  * HW;
  const u16* wrow = t1n + (long)jm * HW;

  f32x4 acc[4][4];
#pragma unroll
  for (int a = 0; a < 4; ++a)
#pragma unroll
    for (int b = 0; b < 4; ++b) acc[a][b] = (f32x4)0.0f;

  // A staging geometry: 1024 chunks of 16B, 4 per thread, XOR swizzle
  int rowc[4], colc[4];
#pragma unroll
  for (int ci = 0; ci < 4; ++ci) {
    int c = t + ci * 256;
    rowc[ci] = c >> 3;
    colc[ci] = ((c & 7) ^ (rowc[ci] & 7)) * 8;
  }

  for (int it = it0; it < it1; ++it) {
    const int k0 = it * 64;
#pragma unroll
    for (int ci = 0; ci < 4; ++ci)
      lds_load16(Ab + (long)(m0 + rowc[ci]) * HW + k0 + colc[ci],
                 &As[(t + ci * 256) * 8]);

    // ---- B-gen: 8 p-values (p8..p8+7), rows jl*8+k. Pure u16 selects. ----
    {
      const int p8 = k0 + pc * 8;
      __attribute__((aligned(16))) u16 Ar[8];
      __attribute__((aligned(16))) u16 Wd[24];     // window = flat [p8-8, p8+16)
      *(uint4*)Ar = *(const uint4*)&arow[p8];
#pragma unroll
      for (int L = 0; L < 3; ++L) {
        int ad = p8 - 8 + L * 8;
        ad = ad < 0 ? 0 : (ad > HW - 8 ? HW - 8 : ad);  // garbage only at masked idx
        *(uint4*)&Wd[L * 8] = *(const uint4*)&wrow[ad];
      }
      const int w0t = p8 % 56;
      int wv[8];
#pragma unroll
      for (int e = 0; e < 8; ++e) { int w = w0t + e; wv[e] = w >= 56 ? w - 56 : w; }
      if (hf == 0) {                           // k = 0..3
#pragma unroll
        for (int k = 0; k < 4; ++k) {
          __attribute__((aligned(16))) u16 v[8];
#pragma unroll
          for (int e = 0; e < 8; ++e)
            v[e] = ((unsigned)(wv[e] + k - 3) < 56u) ? Wd[e + k + 5] : (u16)0;
          *(uint4*)&Bs[(jl * 8 + k) * 64 + (pc ^ k) * 8] = *(const uint4*)v;
        }
      } else {                                 // k = 4..6 + G-row (slot 7)
#pragma unroll
        for (int k = 4; k < 7; ++k) {
          __attribute__((aligned(16))) u16 v[8];
#pragma unroll
          for (int e = 0; e < 8; ++e)
            v[e] = ((unsigned)(wv[e] + k - 3) < 56u) ? Wd[e + k + 5] : (u16)0;
          *(uint4*)&Bs[(jl * 8 + k) * 64 + (pc ^ k) * 8] = *(const uint4*)v;
        }
        // slot 7 = t1[j] row -> produces G[i][j] in output col j*8+7
        *(uint4*)&Bs[(jl * 8 + 7) * 64 + (pc ^ 7) * 8] = *(const uint4*)Ar;
      }
    }
    __syncthreads();
#pragma unroll
    for (int kk = 0; kk < 2; ++kk) {
      const int phys = ((kk * 4 + quad) ^ (lm & 7)) * 8;
      bf16x8 af[4], bv[4];
#pragma unroll
      for (int mi = 0; mi < 4; ++mi)
        af[mi] = *(const bf16x8*)&As[(wm * 64 + mi * 16 + lm) * 64 + phys];
#pragma unroll
      for (int ni = 0; ni < 4; ++ni)
        bv[ni] = *(const bf16x8*)&Bs[(wn * 64 + ni * 16 + lm) * 64 + phys];
#pragma unroll
      for (int mi = 0; mi < 4; ++mi)
#pragma unroll
        for (int ni = 0; ni < 4; ++ni)
          acc[mi][ni] = __builtin_amdgcn_mfma_f32_16x16x32_bf16(
              af[mi], bv[ni], acc[mi][ni], 0, 0, 0);
    }
    __syncthreads();
  }

  // fp32 partial store; C/D layout: col = lane&15, row = quad*4 + reg
  float* Cb = Cp + ((long)ks * NB + nb) * (long)CC * CKP;
#pragma unroll
  for (int mi = 0; mi < 4; ++mi)
#pragma unroll
    for (int ni = 0; ni < 4; ++ni) {
      int rb = m0 + wm * 64 + mi * 16 + quad * 4;
      int cg = n0 + wn * 64 + ni * 16 + lm;
#pragma unroll
      for (int r4 = 0; r4 < 4; ++r4)
        Cb[(long)(rb + r4) * CKP + cg] = acc[mi][ni][r4];
    }
}

// ---------------------------------------------------------------------------
// reduce1: per thread = one j-group (8 cols).  Sums KS1 partials,
// forms t7[jk] = (G - H_k)/56 for k<7 (fp32 subtract), and writes
// S7 = sum_k t7[jk] into slot 7 (consumed by gemm2f's pad MFMA slots).
// grid = NB*CC*CKP/8/256 = 2048
// ---------------------------------------------------------------------------
__global__ void reduce1(const float* __restrict__ p1, u16* __restrict__ t7) {
  const int g = blockIdx.x * 256 + threadIdx.x;   // j-group over NB*CC*CKP/8
  const long S = (long)NB * CC * CKP;             // elements per partial
  const long base = (long)g * 8;
  float a[8];
#pragma unroll
  for (int e = 0; e < 8; ++e) a[e] = 0.0f;
#pragma unroll
  for (int ks = 0; ks < KS1; ++ks) {
    float4 lo = *(const float4*)&p1[ks * S + base];
    float4 hi = *(const float4*)&p1[ks * S + base + 4];
    a[0] += lo.x; a[1] += lo.y; a[2] += lo.z; a[3] += lo.w;
    a[4] += hi.x; a[5] += hi.y; a[6] += hi.z; a[7] += hi.w;
  }
  const float s = 1.0f / 56.0f;
  const float G = a[7];
  __attribute__((aligned(16))) u16 o[8];
  float s7 = 0.0f;
#pragma unroll
  for (int k = 0; k < 7; ++k) {
    float v = (G - a[k]) * s;
    s7 += v;
    o[k] = f2bf(v);
  }
  o[7] = f2bf(s7);
  *(uint4*)&t7[base] = *(const uint4*)o;
}

// ---------------------------------------------------------------------------
// gemm2f (R13): fused NT GEMM, 128x64 tile, BK=64, NO split-K.
//   out[i][p] = s2 * ( sum_{j,k<7} t7[i][jk]*tap[j,k,p]  +  S7[i][j]*xb[j][p] )
// xb term rides in pad slots (A col j*8+7 = S7, B row j*8+7 = raw xb).
// XCD-PINNED flat grid (nb = blockIdx.x & 7): per-XCD working set
// (t7 1 MB + t1n 1.6 MB + xbn 1.6 MB) ~ L2-resident -> tap loads become
// L2 hits instead of streaming from Infinity Cache every iteration.
// R9 2-barrier schedule; inline select-only B-gen (no prefetch regs);
// hoisted tap offsets/masks.  grid = 784 flat
// ---------------------------------------------------------------------------
__global__ __launch_bounds__(256)
void gemm2f(const u16* __restrict__ A, const u16* __restrict__ xb,
            const u16* __restrict__ t1b, float* __restrict__ out) {
  __shared__ u16 As[128 * 64];
  __shared__ u16 Bs[64 * 64];

  // flat block index -> (nb | m0b | n0b), nb fastest => XCD-pinned
  const int bi = blockIdx.x;
  const int nb = bi & 7;
  const int r  = bi >> 3;          // 0..97
  const int m0b = r & 1;
  const int n0b = r >> 1;          // 0..48

  const u16* Ab  = A   + (long)nb * CC * CKP;
  const u16* xbn = xb  + (long)nb * CC * HW;
  const u16* t1n = t1b + (long)nb * CC * HW;
  const int m0 = m0b * 128, n0 = n0b * 64;
  const int t = threadIdx.x;
  const int lane = t & 63, wave = t >> 6;
  const int wm = wave & 1, wn = wave >> 1;        // 2(m) x 2(n of 32)
  const int lm = lane & 15, quad = lane >> 4;

  // B-gen mapping: pr = p-row, jg -> 2 channels per thread per iter
  const int pr = t & 63, jg = t >> 6;
  const int p  = n0 + pr;
  const int h  = p / WW, w = p - h * WW;
  const int h2 = (h + HH - 1) % HH;               // roll +1 on h
  const int w2 = (w + 1) % WW;                    // roll -1 on w
  const int swz = pr & 7;

  // hoisted per-k tap offsets + masks (iter-invariant, depend on p only)
  int toff[7], tmsk[7];
#pragma unroll
  for (int k = 0; k < 7; ++k) {
    int ww = w2 + k - 3;
    int wc = ww < 0 ? 0 : (ww > 55 ? 55 : ww);    // clamped, in-bounds
    toff[k] = h2 * WW + wc;
    tmsk[k] = ((unsigned)ww < 56u);
  }

  f32x4 acc[4][2];
#pragma unroll
  for (int a = 0; a < 4; ++a)
#pragma unroll
    for (int b = 0; b < 2; ++b) acc[a][b] = (f32x4)0.0f;

  int rowc[4], colc[4];
#pragma unroll
  for (int ci = 0; ci < 4; ++ci) {
    int c = t + ci * 256;
    rowc[ci] = c >> 3;
    colc[ci] = ((c & 7) ^ (rowc[ci] & 7)) * 8;
  }

  for (int it = 0; it < 32; ++it) {
    const int k0 = it * 64;
#pragma unroll
    for (int ci = 0; ci < 4; ++ci)
      lds_load16(Ab + (long)(m0 + rowc[ci]) * CKP + k0 + colc[ci],
                 &As[(t + ci * 256) * 8]);

    // ---- B-gen: 2 channels, inline loads, pure u16 selects ----
#pragma unroll
    for (int jj = 0; jj < 2; ++jj) {
      const int jch = it * 8 + jg * 2 + jj;
      const int jmm = (jch + CC - 1) & (CC - 1);
      const u16* trow = t1n + (long)jmm * HW;
      __attribute__((aligned(16))) u16 v[8];
#pragma unroll
      for (int k = 0; k < 7; ++k) {
        u16 tv = trow[toff[k]];
        v[k] = tmsk[k] ? tv : (u16)0;
      }
      v[7] = xbn[(long)jch * HW + p];             // pad slot carries xb term
      *(uint4*)&Bs[pr * 64 + (((jg * 2 + jj) ^ swz) * 8)] = *(const uint4*)v;
    }
    __syncthreads();
#pragma unroll
    for (int kk = 0; kk < 2; ++kk) {
      const int phys = ((kk * 4 + quad) ^ (lm & 7)) * 8;
      bf16x8 af[4], bv[2];
#pragma unroll
      for (int mi = 0; mi < 4; ++mi)
        af[mi] = *(const bf16x8*)&As[(wm * 64 + mi * 16 + lm) * 64 + phys];
#pragma unroll
      for (int ni = 0; ni < 2; ++ni)
        bv[ni] = *(const bf16x8*)&Bs[(wn * 32 + ni * 16 + lm) * 64 + phys];
#pragma unroll
      for (int mi = 0; mi < 4; ++mi)
#pragma unroll
        for (int ni = 0; ni < 2; ++ni)
          acc[mi][ni] = __builtin_amdgcn_mfma_f32_16x16x32_bf16(
              af[mi], bv[ni], acc[mi][ni], 0, 0, 0);
    }
    __syncthreads();
  }

  const float s2 = 0.023622783f;                  // 1/sqrt(1792)
  float* Ob = out + (long)nb * CC * HW;
#pragma unroll
  for (int mi = 0; mi < 4; ++mi)
#pragma unroll
    for (int ni = 0; ni < 2; ++ni) {
      int rb = m0 + wm * 64 + mi * 16 + quad * 4;
      int cg = n0 + wn * 32 + ni * 16 + lm;       // < 3136 always (49*64)
#pragma unroll
      for (int r4 = 0; r4 < 4; ++r4)
        Ob[(long)(rb + r4) * HW + cg] = acc[mi][ni][r4] * s2;
    }
}

// ---------------------------------------------------------------------------
// Pipeline: pass1 -> gemm1f -> reduce1 -> gemm2f(-> d_out).  ~101 MB footprint.
// ---------------------------------------------------------------------------
extern "C" void kernel_launch(void* const* d_in, const int* in_sizes, int n_in,
                              void* d_out, int out_size, void* d_ws, size_t ws_size,
                              hipStream_t stream) {
  const float* x   = (const float*)d_in[0];   // (8,256,56,56)
  const float* p1w = (const float*)d_in[1];   // (1,256,56,56)

  char* ws = (char*)d_ws;
  size_t o = 0;
  u16* xb  = (u16*)(ws + o); o += (size_t)NB * CC * HW * 2;          //  12.8 MB
  u16* t1b = (u16*)(ws + o); o += (size_t)NB * CC * HW * 2;          //  12.8 MB
  u16* t7  = (u16*)(ws + o); o += (size_t)NB * CC * CKP * 2;         //   8.4 MB
  float* p1 = (float*)(ws + o); o += (size_t)KS1 * NB * CC * CKP * 4; // 67.1 MB

  pass1<<<NB * CC * HW / 4 / 256, 256, 0, stream>>>(x, p1w, t1b, xb);
  gemm1f<<<NB * KS1 * 2 * 16, 256, 0, stream>>>(xb, t1b, p1);
  reduce1<<<NB * CC * CKP / 8 / 256, 256, 0, stream>>>(p1, t7);
  gemm2f<<<NB * 2 * 49, 256, 0, stream>>>(t7, xb, t1b, (float*)d_out);
}

// Round 6
// 177.762 us; speedup vs baseline: 1.4432x; 1.0441x over previous
//
#include <hip/hip_runtime.h>

typedef unsigned short u16;
typedef __bf16 bf16x8 __attribute__((ext_vector_type(8)));
typedef float f32x4 __attribute__((ext_vector_type(4)));

#define HH  56
#define WW  56
#define HW  3136      // 56*56
#define CC  256
#define NB  8
#define CKP 2048      // c*7 padded to c*8: channel j's taps = cols j*8..j*8+7
#define KS1 4         // split-K factor GEMM1 (49 iters -> 12/12/12/13)

// round-to-nearest-even fp32 -> bf16 (bit pattern) — for non-hot paths
__device__ __forceinline__ u16 f2bf(float f) {
  unsigned int u = __float_as_uint(f);
  u += 0x7fffu + ((u >> 16) & 1u);
  return (u16)(u >> 16);
}
__device__ __forceinline__ float bf2f(u16 v) {
  return __uint_as_float((unsigned)v << 16);
}

// async global->LDS DMA, 16B per lane; dest = wave-uniform base + lane*16
__device__ __forceinline__ void lds_load16(const void* g, void* l) {
  __builtin_amdgcn_global_load_lds(
      (const __attribute__((address_space(1))) void*)g,
      (__attribute__((address_space(3))) void*)l, 16, 0, 0);
}

// ---------------------------------------------------------------------------
// pass1: t1b = bf16(p1w * x), xb = bf16(x).  Fully coalesced float4 reads.
// grid = N*C*HW/4/256 = 6272
// ---------------------------------------------------------------------------
__global__ void pass1(const float* __restrict__ x, const float* __restrict__ p1w,
                      u16* __restrict__ t1b, u16* __restrict__ xb) {
  int i = blockIdx.x * 256 + threadIdx.x;        // over N*C*HW/4
  int cw = i % (CC * HW / 4);                    // p1w broadcast over n
  float4 xv = ((const float4*)x)[i];
  float4 wv = ((const float4*)p1w)[cw];
  uint2 xo = make_uint2((unsigned)f2bf(xv.x) | ((unsigned)f2bf(xv.y) << 16),
                        (unsigned)f2bf(xv.z) | ((unsigned)f2bf(xv.w) << 16));
  ((uint2*)xb)[i] = xo;
  uint2 to = make_uint2((unsigned)f2bf(xv.x * wv.x) | ((unsigned)f2bf(xv.y * wv.y) << 16),
                        (unsigned)f2bf(xv.z * wv.z) | ((unsigned)f2bf(xv.w * wv.w) << 16));
  ((uint2*)t1b)[i] = to;
}

// ---------------------------------------------------------------------------
// gemm1f (R13, unchanged): fused NT GEMM (split-K=4), 128x128 tile, BK=64.
// XCD-PINNED flat grid (nb = blockIdx.x & 7).  2-barrier schedule,
// select-only B-gen.  B rows j*8+k (k<7) = masked taps of t2[j];
// row j*8+7 = t1[j] (G-row).  grid = 1024 flat
// ---------------------------------------------------------------------------
__global__ __launch_bounds__(256)
void gemm1f(const u16* __restrict__ A, const u16* __restrict__ t1b,
            float* __restrict__ Cp) {
  __shared__ u16 As[128 * 64];
  __shared__ u16 Bs[128 * 64];

  const int bi = blockIdx.x;
  const int nb = bi & 7;
  const int r  = bi >> 3;          // 0..127
  const int ks = r & 3;
  const int r2 = r >> 2;           // 0..31
  const int m0b = r2 & 1;
  const int n0b = r2 >> 1;         // 0..15

  const int it0 = 49 * ks / KS1, it1 = 49 * (ks + 1) / KS1;
  const u16* Ab  = A   + (long)nb * CC * HW;
  const u16* t1n = t1b + (long)nb * CC * HW;
  const int m0 = m0b * 128, n0 = n0b * 128;
  const int jb = n0b * 16;                        // first channel of tile
  const int t = threadIdx.x;
  const int lane = t & 63, wave = t >> 6;
  const int wm = wave & 1, wn = wave >> 1;        // 2x2 waves, 64x64 each
  const int lm = lane & 15, quad = lane >> 4;

  // B-gen mapping
  const int jl = (t >> 3) & 15, pc = t & 7, hf = t >> 7;   // hf wave-uniform
  const int j  = jb + jl;
  const int jm = (j + CC - 1) & (CC - 1);
  const u16* arow = t1n + (long)j  * HW;
  const u16* wrow = t1n + (long)jm * HW;

  f32x4 acc[4][4];
#pragma unroll
  for (int a = 0; a < 4; ++a)
#pragma unroll
    for (int b = 0; b < 4; ++b) acc[a][b] = (f32x4)0.0f;

  // A staging geometry: 1024 chunks of 16B, 4 per thread, XOR swizzle
  int rowc[4], colc[4];
#pragma unroll
  for (int ci = 0; ci < 4; ++ci) {
    int c = t + ci * 256;
    rowc[ci] = c >> 3;
    colc[ci] = ((c & 7) ^ (rowc[ci] & 7)) * 8;
  }

  for (int it = it0; it < it1; ++it) {
    const int k0 = it * 64;
#pragma unroll
    for (int ci = 0; ci < 4; ++ci)
      lds_load16(Ab + (long)(m0 + rowc[ci]) * HW + k0 + colc[ci],
                 &As[(t + ci * 256) * 8]);

    // ---- B-gen: 8 p-values (p8..p8+7), rows jl*8+k. Pure u16 selects. ----
    {
      const int p8 = k0 + pc * 8;
      __attribute__((aligned(16))) u16 Ar[8];
      __attribute__((aligned(16))) u16 Wd[24];     // window = flat [p8-8, p8+16)
      *(uint4*)Ar = *(const uint4*)&arow[p8];
#pragma unroll
      for (int L = 0; L < 3; ++L) {
        int ad = p8 - 8 + L * 8;
        ad = ad < 0 ? 0 : (ad > HW - 8 ? HW - 8 : ad);  // garbage only at masked idx
        *(uint4*)&Wd[L * 8] = *(const uint4*)&wrow[ad];
      }
      const int w0t = p8 % 56;
      int wv[8];
#pragma unroll
      for (int e = 0; e < 8; ++e) { int w = w0t + e; wv[e] = w >= 56 ? w - 56 : w; }
      if (hf == 0) {                           // k = 0..3
#pragma unroll
        for (int k = 0; k < 4; ++k) {
          __attribute__((aligned(16))) u16 v[8];
#pragma unroll
          for (int e = 0; e < 8; ++e)
            v[e] = ((unsigned)(wv[e] + k - 3) < 56u) ? Wd[e + k + 5] : (u16)0;
          *(uint4*)&Bs[(jl * 8 + k) * 64 + (pc ^ k) * 8] = *(const uint4*)v;
        }
      } else {                                 // k = 4..6 + G-row (slot 7)
#pragma unroll
        for (int k = 4; k < 7; ++k) {
          __attribute__((aligned(16))) u16 v[8];
#pragma unroll
          for (int e = 0; e < 8; ++e)
            v[e] = ((unsigned)(wv[e] + k - 3) < 56u) ? Wd[e + k + 5] : (u16)0;
          *(uint4*)&Bs[(jl * 8 + k) * 64 + (pc ^ k) * 8] = *(const uint4*)v;
        }
        // slot 7 = t1[j] row -> produces G[i][j] in output col j*8+7
        *(uint4*)&Bs[(jl * 8 + 7) * 64 + (pc ^ 7) * 8] = *(const uint4*)Ar;
      }
    }
    __syncthreads();
#pragma unroll
    for (int kk = 0; kk < 2; ++kk) {
      const int phys = ((kk * 4 + quad) ^ (lm & 7)) * 8;
      bf16x8 af[4], bv[4];
#pragma unroll
      for (int mi = 0; mi < 4; ++mi)
        af[mi] = *(const bf16x8*)&As[(wm * 64 + mi * 16 + lm) * 64 + phys];
#pragma unroll
      for (int ni = 0; ni < 4; ++ni)
        bv[ni] = *(const bf16x8*)&Bs[(wn * 64 + ni * 16 + lm) * 64 + phys];
#pragma unroll
      for (int mi = 0; mi < 4; ++mi)
#pragma unroll
        for (int ni = 0; ni < 4; ++ni)
          acc[mi][ni] = __builtin_amdgcn_mfma_f32_16x16x32_bf16(
              af[mi], bv[ni], acc[mi][ni], 0, 0, 0);
    }
    __syncthreads();
  }

  // fp32 partial store; C/D layout: col = lane&15, row = quad*4 + reg
  float* Cb = Cp + ((long)ks * NB + nb) * (long)CC * CKP;
#pragma unroll
  for (int mi = 0; mi < 4; ++mi)
#pragma unroll
    for (int ni = 0; ni < 4; ++ni) {
      int rb = m0 + wm * 64 + mi * 16 + quad * 4;
      int cg = n0 + wn * 64 + ni * 16 + lm;
#pragma unroll
      for (int r4 = 0; r4 < 4; ++r4)
        Cb[(long)(rb + r4) * CKP + cg] = acc[mi][ni][r4];
    }
}

// ---------------------------------------------------------------------------
// reduce1 (unchanged): sums KS1 partials, t7[jk]=(G-H_k)/56, S7 in slot 7.
// grid = NB*CC*CKP/8/256 = 2048
// ---------------------------------------------------------------------------
__global__ void reduce1(const float* __restrict__ p1, u16* __restrict__ t7) {
  const int g = blockIdx.x * 256 + threadIdx.x;   // j-group over NB*CC*CKP/8
  const long S = (long)NB * CC * CKP;             // elements per partial
  const long base = (long)g * 8;
  float a[8];
#pragma unroll
  for (int e = 0; e < 8; ++e) a[e] = 0.0f;
#pragma unroll
  for (int ks = 0; ks < KS1; ++ks) {
    float4 lo = *(const float4*)&p1[ks * S + base];
    float4 hi = *(const float4*)&p1[ks * S + base + 4];
    a[0] += lo.x; a[1] += lo.y; a[2] += lo.z; a[3] += lo.w;
    a[4] += hi.x; a[5] += hi.y; a[6] += hi.z; a[7] += hi.w;
  }
  const float s = 1.0f / 56.0f;
  const float G = a[7];
  __attribute__((aligned(16))) u16 o[8];
  float s7 = 0.0f;
#pragma unroll
  for (int k = 0; k < 7; ++k) {
    float v = (G - a[k]) * s;
    s7 += v;
    o[k] = f2bf(v);
  }
  o[7] = f2bf(s7);
  *(uint4*)&t7[base] = *(const uint4*)o;
}

// ---------------------------------------------------------------------------
// gemm2f (R14): fused NT GEMM, 128x64 tile, BK=64, XCD-pinned flat grid.
//   out[i][p] = s2 * ( sum_{j,k<7} t7[i][jk]*tap[j,k,p]  +  S7[i][j]*xb[j][p] )
// NEW: B-source LDS STAGING — per iteration the 8 channels' tap rows
// (2 h2-rows x 56 bf16 each = 1.8 KB) and xb rows (8x64 = 1 KB) are DMA'd
// one iteration ahead into double-buffered LDS by waves 1-3 (~11 wave-level
// global_load_lds).  B-gen then does 16 LDS u16 reads + selects per thread:
// ZERO per-thread global loads (was 16/thread/iter = the latency chain).
// grid = 784 flat
// ---------------------------------------------------------------------------
__global__ __launch_bounds__(256)
void gemm2f(const u16* __restrict__ A, const u16* __restrict__ xb,
            const u16* __restrict__ t1b, float* __restrict__ out) {
  __shared__ u16 As[128 * 64];                    // 16 KB
  __shared__ u16 Bs[64 * 64];                     //  8 KB
  __shared__ __attribute__((aligned(16))) u16 Rs0[896], Rs1[896]; // [8ch][2row][56]
  __shared__ __attribute__((aligned(16))) u16 Xs0[512], Xs1[512]; // [8ch][64]

  // flat block index -> (nb | m0b | n0b), nb fastest => XCD-pinned
  const int bi = blockIdx.x;
  const int nb = bi & 7;
  const int r  = bi >> 3;          // 0..97
  const int m0b = r & 1;
  const int n0b = r >> 1;          // 0..48

  const u16* Ab  = A   + (long)nb * CC * CKP;
  const u16* xbn = xb  + (long)nb * CC * HW;
  const u16* t1n = t1b + (long)nb * CC * HW;
  const int m0 = m0b * 128, n0 = n0b * 64;
  const int t = threadIdx.x;
  const int lane = t & 63, wave = t >> 6;
  const int wm = wave & 1, wn = wave >> 1;        // 2(m) x 2(n of 32)
  const int lm = lane & 15, quad = lane >> 4;

  // B-gen read mapping: pr = p-row, jg -> 2 channels per thread per iter
  const int pr = t & 63, jg = t >> 6;
  const int p  = n0 + pr;
  const int h  = p / WW, w = p - h * WW;
  const int w2 = (w + 1) % WW;                    // roll -1 on w
  const int swz = pr & 7;
  const int h_lo = n0 / WW;
  const int slot = h - h_lo;                      // 0 or 1 (64 p span 2 rows)

  // iter-invariant LDS offsets into Rs/Xs for the 16 tap/xb reads
  int roff[2][7], rmsk[7];
#pragma unroll
  for (int k = 0; k < 7; ++k) {
    int ww = w2 + k - 3;
    int wc = ww < 0 ? 0 : (ww > 55 ? 55 : ww);    // clamped, in-bounds
    rmsk[k] = ((unsigned)ww < 56u);
#pragma unroll
    for (int jj = 0; jj < 2; ++jj)
      roff[jj][k] = ((jg * 2 + jj) * 2 + slot) * 56 + wc;
  }
  const int xoff0 = (jg * 2 + 0) * 64 + pr;
  const int xoff1 = (jg * 2 + 1) * 64 + pr;

  // staging descriptors (wave roles): wave1 -> Xs, wave2 -> Rs[0:64),
  // wave3 (lane<48) -> Rs[64:112).  Rs chunk c: ch=c/14, s=(c%14)/7, i=c%7.
  // Xs chunk c: ch=c>>3, i=c&7.  All 16B aligned (112B rows, 128B xb rows).
  long stSrcOff = 0;     // iter-invariant part of source offset (u16 units)
  int  stCh = 0;         // channel index 0..7 (jch = it*8 + stCh; Rs: jmm)
  bool stR = false, stX = false;
  {
    if (wave == 1) {
      stX = true; stCh = lane >> 3;
      stSrcOff = n0 + (lane & 7) * 8;
    } else if (wave == 2 || (wave == 3 && lane < 48)) {
      stR = true;
      int c = (wave == 2) ? lane : 64 + lane;
      stCh = c / 14;
      int rem = c - stCh * 14;
      int s = rem / 7, i = rem - s * 7;
      int h2s = ((h_lo + s) + HH - 1) % HH;       // h_lo+s <= 55 always
      stSrcOff = h2s * 56 + i * 8;
    }
  }

  f32x4 acc[4][2];
#pragma unroll
  for (int a = 0; a < 4; ++a)
#pragma unroll
    for (int b = 0; b < 2; ++b) acc[a][b] = (f32x4)0.0f;

  int rowc[4], colc[4];
#pragma unroll
  for (int ci = 0; ci < 4; ++ci) {
    int c = t + ci * 256;
    rowc[ci] = c >> 3;
    colc[ci] = ((c & 7) ^ (rowc[ci] & 7)) * 8;
  }

#define DMAA(itn) do { const int k0_ = (itn) * 64;                             \
    _Pragma("unroll")                                                          \
    for (int ci = 0; ci < 4; ++ci)                                             \
      lds_load16(Ab + (long)(m0 + rowc[ci]) * CKP + k0_ + colc[ci],            \
                 &As[(t + ci * 256) * 8]); } while (0)

#define STAGE(RsD, XsD, itn) do {                                              \
    if (stX)                                                                   \
      lds_load16(xbn + (long)((itn) * 8 + stCh) * HW + stSrcOff,               \
                 &XsD[lane * 8]);                                              \
    else if (stR) {                                                            \
      const int jmm_ = ((itn) * 8 + stCh + CC - 1) & (CC - 1);                 \
      lds_load16(t1n + (long)jmm_ * HW + stSrcOff,                             \
                 (wave == 2) ? &RsD[lane * 8] : &RsD[512 + lane * 8]);         \
    } } while (0)

#define BGEN(RsS, XsS) do {                                                    \
    __attribute__((aligned(16))) u16 v0[8], v1[8];                             \
    _Pragma("unroll")                                                          \
    for (int k = 0; k < 7; ++k) {                                              \
      u16 a_ = RsS[roff[0][k]], b_ = RsS[roff[1][k]];                          \
      v0[k] = rmsk[k] ? a_ : (u16)0;                                           \
      v1[k] = rmsk[k] ? b_ : (u16)0;                                           \
    }                                                                          \
    v0[7] = XsS[xoff0];                                                        \
    v1[7] = XsS[xoff1];                                                        \
    *(uint4*)&Bs[pr * 64 + (((jg * 2 + 0) ^ swz) * 8)] = *(const uint4*)v0;    \
    *(uint4*)&Bs[pr * 64 + (((jg * 2 + 1) ^ swz) * 8)] = *(const uint4*)v1;    \
  } while (0)

#define MFMA2(void0) do {                                                      \
    _Pragma("unroll")                                                          \
    for (int kk = 0; kk < 2; ++kk) {                                           \
      const int phys = ((kk * 4 + quad) ^ (lm & 7)) * 8;                       \
      bf16x8 af[4], bv[2];                                                     \
      _Pragma("unroll")                                                        \
      for (int mi = 0; mi < 4; ++mi)                                           \
        af[mi] = *(const bf16x8*)&As[(wm * 64 + mi * 16 + lm) * 64 + phys];    \
      _Pragma("unroll")                                                        \
      for (int ni = 0; ni < 2; ++ni)                                           \
        bv[ni] = *(const bf16x8*)&Bs[(wn * 32 + ni * 16 + lm) * 64 + phys];    \
      _Pragma("unroll")                                                        \
      for (int mi = 0; mi < 4; ++mi)                                           \
        _Pragma("unroll")                                                      \
        for (int ni = 0; ni < 2; ++ni)                                         \
          acc[mi][ni] = __builtin_amdgcn_mfma_f32_16x16x32_bf16(               \
              af[mi], bv[ni], acc[mi][ni], 0, 0, 0);                           \
    } } while (0)

  // ---- prologue: stage sources for it=0 ----
  STAGE(Rs0, Xs0, 0);
  __syncthreads();                 // drains stage(0)

  // ---- main: 32 iterations, pair-unrolled for static buffer names ----
  for (int itp = 0; itp < 16; ++itp) {
    const int itE = itp * 2;
    // even region: consume Rs0/Xs0(itE), stage Rs1/Xs1(itE+1)
    DMAA(itE);
    STAGE(Rs1, Xs1, itE + 1);      // itE+1 <= 31 always
    BGEN(Rs0, Xs0);
    __syncthreads();               // drains A(itE) + stage(itE+1)
    MFMA2();
    __syncthreads();
    // odd region: consume Rs1/Xs1(itE+1), stage Rs0/Xs0(itE+2)
    DMAA(itE + 1);
    if (itE + 2 < 32) STAGE(Rs0, Xs0, itE + 2);
    BGEN(Rs1, Xs1);
    __syncthreads();
    MFMA2();
    __syncthreads();
  }

#undef DMAA
#undef STAGE
#undef BGEN
#undef MFMA2

  const float s2 = 0.023622783f;                  // 1/sqrt(1792)
  float* Ob = out + (long)nb * CC * HW;
#pragma unroll
  for (int mi = 0; mi < 4; ++mi)
#pragma unroll
    for (int ni = 0; ni < 2; ++ni) {
      int rb = m0 + wm * 64 + mi * 16 + quad * 4;
      int cg = n0 + wn * 32 + ni * 16 + lm;       // < 3136 always (49*64)
#pragma unroll
      for (int r4 = 0; r4 < 4; ++r4)
        Ob[(long)(rb + r4) * HW + cg] = acc[mi][ni][r4] * s2;
    }
}

// ---------------------------------------------------------------------------
// Pipeline: pass1 -> gemm1f -> reduce1 -> gemm2f(-> d_out).  ~101 MB footprint.
// ---------------------------------------------------------------------------
extern "C" void kernel_launch(void* const* d_in, const int* in_sizes, int n_in,
                              void* d_out, int out_size, void* d_ws, size_t ws_size,
                              hipStream_t stream) {
  const float* x   = (const float*)d_in[0];   // (8,256,56,56)
  const float* p1w = (const float*)d_in[1];   // (1,256,56,56)

  char* ws = (char*)d_ws;
  size_t o = 0;
  u16* xb  = (u16*)(ws + o); o += (size_t)NB * CC * HW * 2;          //  12.8 MB
  u16* t1b = (u16*)(ws + o); o += (size_t)NB * CC * HW * 2;          //  12.8 MB
  u16* t7  = (u16*)(ws + o); o += (size_t)NB * CC * CKP * 2;         //   8.4 MB
  float* p1 = (float*)(ws + o); o += (size_t)KS1 * NB * CC * CKP * 4; // 67.1 MB

  pass1<<<NB * CC * HW / 4 / 256, 256, 0, stream>>>(x, p1w, t1b, xb);
  gemm1f<<<NB * KS1 * 2 * 16, 256, 0, stream>>>(xb, t1b, p1);
  reduce1<<<NB * CC * CKP / 8 / 256, 256, 0, stream>>>(p1, t7);
  gemm2f<<<NB * 2 * 49, 256, 0, stream>>>(t7, xb, t1b, (float*)d_out);
}